// Round 1
// baseline (195.544 us; speedup 1.0000x reference)
//
#include <hip/hip_runtime.h>

// Problem constants (fixed by reference setup_inputs)
#define NB 8192      // rows of X and Y
#define DD 512       // feature dim
#define INV_T 20.609929155556618f   // (float)(log2(e)/0.07)

typedef short bf16x8 __attribute__((ext_vector_type(8)));  // 8 bf16 in 4 VGPRs
typedef float f32x4  __attribute__((ext_vector_type(4)));

// round-to-nearest-even fp32 -> bf16 (no NaN handling needed: inputs finite)
__device__ static inline unsigned short f2bf(float f) {
  unsigned int u = __float_as_uint(f);
  u += 0x7fff + ((u >> 16) & 1);
  return (unsigned short)(u >> 16);
}

// async global->LDS, 16B per lane; lds base must be wave-uniform
__device__ static inline void async16(void* lds, const void* g) {
  __builtin_amdgcn_global_load_lds(
      (const __attribute__((address_space(1))) unsigned int*)g,
      (__attribute__((address_space(3))) unsigned int*)lds, 16, 0, 0);
}

// -------- kernel 1: fused L2-normalize (fp32->bf16) + diagonal Sv --------
// one wave per row; 512 floats = 8 per lane (two float4 loads, coalesced)
__global__ __launch_bounds__(256) void norm_kernel(
    const float* __restrict__ X, const float* __restrict__ Y,
    unsigned short* __restrict__ Xnb, unsigned short* __restrict__ Ynb,
    float* __restrict__ Sv) {
  const int wv   = threadIdx.x >> 6;
  const int lane = threadIdx.x & 63;
  const int row  = blockIdx.x * 4 + wv;
  const float4* x4 = (const float4*)(X + (size_t)row * DD);
  const float4* y4 = (const float4*)(Y + (size_t)row * DD);
  float4 xa = x4[lane * 2], xb = x4[lane * 2 + 1];
  float4 ya = y4[lane * 2], yb = y4[lane * 2 + 1];
  float xs[8] = {xa.x, xa.y, xa.z, xa.w, xb.x, xb.y, xb.z, xb.w};
  float ys[8] = {ya.x, ya.y, ya.z, ya.w, yb.x, yb.y, yb.z, yb.w};
  float ssx = 0.f, ssy = 0.f, sxy = 0.f;
#pragma unroll
  for (int k = 0; k < 8; ++k) {
    ssx += xs[k] * xs[k];
    ssy += ys[k] * ys[k];
    sxy += xs[k] * ys[k];
  }
#pragma unroll
  for (int m = 1; m < 64; m <<= 1) {
    ssx += __shfl_xor(ssx, m);
    ssy += __shfl_xor(ssy, m);
    sxy += __shfl_xor(sxy, m);
  }
  const float rnx = 1.0f / sqrtf(ssx);
  const float rny = 1.0f / sqrtf(ssy);
  unsigned short ox[8], oy[8];
#pragma unroll
  for (int k = 0; k < 8; ++k) {
    ox[k] = f2bf(xs[k] * rnx);
    oy[k] = f2bf(ys[k] * rny);
  }
  *(uint4*)(Xnb + (size_t)row * DD + lane * 8) = *(const uint4*)ox;
  *(uint4*)(Ynb + (size_t)row * DD + lane * 8) = *(const uint4*)oy;
  if (lane == 0) Sv[row] = sxy * rnx * rny * INV_T - INV_T;  // fp32 diagonal
}

// -------- kernel 2: 128x128 bf16 MFMA tile + exp2 + row/col partial sums ----
// grid (64 cols, 64 rows), 256 threads = 4 waves in 2x2; wave tile 64x64.
// S = Xn * Yn^T  (NT gemm: both row-major [8192][512])
__global__ __launch_bounds__(256, 2) void gemm_kernel(
    const unsigned short* __restrict__ Xnb, const unsigned short* __restrict__ Ynb,
    float* __restrict__ rowp, float* __restrict__ colp) {
  __shared__ __align__(16) char sAB[32768];      // sA [0,16K), sB [16K,32K)
  __shared__ float rowpart[2][128];              // [wc][row-in-tile]
  __shared__ float colpart[2][128];              // [wr][col-in-tile]

  const int t    = threadIdx.x;
  const int wv   = t >> 6;
  const int lane = t & 63;
  const int l16  = lane & 15;
  const int lg   = lane >> 4;
  const int wr   = wv >> 1, wc = wv & 1;
  const int br   = blockIdx.y, bc = blockIdx.x;
  const size_t rowA0 = (size_t)br * 128;
  const size_t rowB0 = (size_t)bc * 128;

  f32x4 acc[4][4] = {};

  for (int kt = 0; kt < 8; ++kt) {          // K = 512 = 8 * BK(64)
    const int kb = kt * 64;
    // --- stage A,B tiles (16KB each) via global_load_lds, width 16 ---
#pragma unroll
    for (int it = 0; it < 4; ++it) {
      const int obase = it * 4096 + wv * 1024;   // wave-uniform LDS dest
      const int o = obase + lane * 16;           // this lane's 16B slot
      const int r  = o >> 7;                     // tile row (128B per row)
      const int cb = o & 127;                    // byte within row
      const char* gA = (const char*)(Xnb + (rowA0 + r) * DD + kb) + cb;
      const char* gB = (const char*)(Ynb + (rowB0 + r) * DD + kb) + cb;
      async16(sAB + obase, gA);
      async16(sAB + 16384 + obase, gB);
    }
    __syncthreads();   // compiler drains vmcnt before barrier
    // --- MFMA: 2 k-slices x 4x4 fragments of 16x16x32 ---
#pragma unroll
    for (int ks = 0; ks < 2; ++ks) {
      bf16x8 af[4], bfv[4];
#pragma unroll
      for (int i = 0; i < 4; ++i) {
        const int ra = wr * 64 + i * 16 + l16;
        af[i] = *(const bf16x8*)(sAB + ra * 128 + ks * 64 + lg * 16);
        const int rb = wc * 64 + i * 16 + l16;
        bfv[i] = *(const bf16x8*)(sAB + 16384 + rb * 128 + ks * 64 + lg * 16);
      }
#pragma unroll
      for (int i = 0; i < 4; ++i)
#pragma unroll
        for (int j = 0; j < 4; ++j)
          acc[i][j] = __builtin_amdgcn_mfma_f32_16x16x32_bf16(af[i], bfv[j],
                                                              acc[i][j], 0, 0, 0);
    }
    __syncthreads();
  }

  // --- epilogue: E = exp2(S*it - it); reduce rows & cols inside the wave ---
  // D layout (m89-verified): col = l16, row = lg*4 + reg, per 16x16 fragment
  float colacc[4] = {0.f, 0.f, 0.f, 0.f};
#pragma unroll
  for (int i = 0; i < 4; ++i) {
    float rowacc[4] = {0.f, 0.f, 0.f, 0.f};
#pragma unroll
    for (int j = 0; j < 4; ++j)
#pragma unroll
      for (int r = 0; r < 4; ++r) {
        const float e = exp2f(fmaf(acc[i][j][r], INV_T, -INV_T));
        rowacc[r] += e;     // partial over this lane's 4 cols (j loop)
        colacc[j] += e;     // partial over this lane's 16 rows (i,r loops)
      }
#pragma unroll
    for (int r = 0; r < 4; ++r) {     // sum across the 16 lanes sharing a row
      float v = rowacc[r];
      v += __shfl_xor(v, 1); v += __shfl_xor(v, 2);
      v += __shfl_xor(v, 4); v += __shfl_xor(v, 8);
      if (l16 == 0) rowpart[wc][wr * 64 + i * 16 + lg * 4 + r] = v;
    }
  }
#pragma unroll
  for (int j = 0; j < 4; ++j) {       // sum across the 4 lane-groups per col
    float v = colacc[j];
    v += __shfl_xor(v, 16); v += __shfl_xor(v, 32);
    if (lg == 0) colpart[wr][wc * 64 + j * 16 + l16] = v;
  }
  __syncthreads();
  if (t < 128) {
    rowp[(size_t)bc * NB + rowA0 + t] = rowpart[0][t] + rowpart[1][t];
  } else {
    const int c = t - 128;
    colp[(size_t)br * NB + rowB0 + c] = colpart[0][c] + colpart[1][c];
  }
}

// -------- kernel 3: reduce 64 partials per row/col, compute loss --------
__global__ __launch_bounds__(256) void loss_kernel(
    const float* __restrict__ rowp, const float* __restrict__ colp,
    const float* __restrict__ Sv, float* __restrict__ out) {
  __shared__ float wsum[4];
  const int i = blockIdx.x * 256 + threadIdx.x;   // grid 32 -> all 8192 rows
  float rs = 0.f, cs = 0.f;
  for (int b = 0; b < 64; ++b) {
    rs += rowp[(size_t)b * NB + i];
    cs += colp[(size_t)b * NB + i];
  }
  float v = 2.f * Sv[i] - logf(rs) - logf(cs);    // logit_i
#pragma unroll
  for (int m = 1; m < 64; m <<= 1) v += __shfl_xor(v, m);
  if ((threadIdx.x & 63) == 0) wsum[threadIdx.x >> 6] = v;
  __syncthreads();
  if (threadIdx.x == 0) {
    const float s = wsum[0] + wsum[1] + wsum[2] + wsum[3];
    atomicAdd(out, s * (-1.0f / (2.0f * NB)));    // loss = -mean(logits)/2
  }
}

extern "C" void kernel_launch(void* const* d_in, const int* in_sizes, int n_in,
                              void* d_out, int out_size, void* d_ws, size_t ws_size,
                              hipStream_t stream) {
  const float* X = (const float*)d_in[0];   // image_features
  const float* Y = (const float*)d_in[1];   // text_features
  char* ws = (char*)d_ws;
  // workspace layout (21.0 MB total)
  unsigned short* Xnb = (unsigned short*)(ws);                       // 8 MB
  unsigned short* Ynb = (unsigned short*)(ws + 8388608);             // 8 MB
  float* Sv   = (float*)(ws + 16777216);                             // 32 KB
  float* rowp = (float*)(ws + 16777216 + 32768);                     // 2 MB
  float* colp = (float*)(ws + 16777216 + 32768 + 2097152);           // 2 MB
  float* out  = (float*)d_out;

  hipMemsetAsync(d_out, 0, sizeof(float), stream);  // d_out is 0xAA-poisoned
  norm_kernel<<<NB / 4, 256, 0, stream>>>(X, Y, Xnb, Ynb, Sv);
  gemm_kernel<<<dim3(64, 64), 256, 0, stream>>>(Xnb, Ynb, rowp, colp);
  loss_kernel<<<32, 256, 0, stream>>>(rowp, colp, Sv, out);
}

// Round 3
// 182.749 us; speedup vs baseline: 1.0700x; 1.0700x over previous
//
#include <hip/hip_runtime.h>

// Problem constants (fixed by reference setup_inputs)
#define NB 8192      // rows of X and Y
#define DD 512       // feature dim
#define INV_T 20.609929155556618f   // (float)(log2(e)/0.07)

typedef short bf16x8 __attribute__((ext_vector_type(8)));  // 8 bf16 in 4 VGPRs
typedef float f32x4  __attribute__((ext_vector_type(4)));

// round-to-nearest-even fp32 -> bf16 (no NaN handling needed: inputs finite)
__device__ static inline unsigned short f2bf(float f) {
  unsigned int u = __float_as_uint(f);
  u += 0x7fff + ((u >> 16) & 1);
  return (unsigned short)(u >> 16);
}

// async global->LDS, 16B per lane; lds base must be wave-uniform
__device__ static inline void async16(void* lds, const void* g) {
  __builtin_amdgcn_global_load_lds(
      (const __attribute__((address_space(1))) unsigned int*)g,
      (__attribute__((address_space(3))) unsigned int*)lds, 16, 0, 0);
}

// -------- kernel 1: fused L2-normalize (fp32->bf16) + diagonal Sv --------
// one wave per row; 512 floats = 8 per lane (two float4 loads, coalesced)
__global__ __launch_bounds__(256) void norm_kernel(
    const float* __restrict__ X, const float* __restrict__ Y,
    unsigned short* __restrict__ Xnb, unsigned short* __restrict__ Ynb,
    float* __restrict__ Sv) {
  const int wv   = threadIdx.x >> 6;
  const int lane = threadIdx.x & 63;
  const int row  = blockIdx.x * 4 + wv;
  const float4* x4 = (const float4*)(X + (size_t)row * DD);
  const float4* y4 = (const float4*)(Y + (size_t)row * DD);
  float4 xa = x4[lane * 2], xb = x4[lane * 2 + 1];
  float4 ya = y4[lane * 2], yb = y4[lane * 2 + 1];
  float xs[8] = {xa.x, xa.y, xa.z, xa.w, xb.x, xb.y, xb.z, xb.w};
  float ys[8] = {ya.x, ya.y, ya.z, ya.w, yb.x, yb.y, yb.z, yb.w};
  float ssx = 0.f, ssy = 0.f, sxy = 0.f;
#pragma unroll
  for (int k = 0; k < 8; ++k) {
    ssx += xs[k] * xs[k];
    ssy += ys[k] * ys[k];
    sxy += xs[k] * ys[k];
  }
#pragma unroll
  for (int m = 1; m < 64; m <<= 1) {
    ssx += __shfl_xor(ssx, m);
    ssy += __shfl_xor(ssy, m);
    sxy += __shfl_xor(sxy, m);
  }
  const float rnx = 1.0f / sqrtf(ssx);
  const float rny = 1.0f / sqrtf(ssy);
  unsigned short ox[8], oy[8];
#pragma unroll
  for (int k = 0; k < 8; ++k) {
    ox[k] = f2bf(xs[k] * rnx);
    oy[k] = f2bf(ys[k] * rny);
  }
  *(uint4*)(Xnb + (size_t)row * DD + lane * 8) = *(const uint4*)ox;
  *(uint4*)(Ynb + (size_t)row * DD + lane * 8) = *(const uint4*)oy;
  if (lane == 0) Sv[row] = sxy * rnx * rny * INV_T - INV_T;  // fp32 diagonal
}

// -------- kernel 2: 128x128 bf16 MFMA tile + exp2 + row/col partial sums ----
// m97 structure: BK=32 (64B LDS rows -> near-conflict-free ds_read_b128).
// grid (64 cols, 64 rows), 256 threads = 4 waves in 2x2; wave tile 64x64.
// S = Xn * Yn^T  (NT gemm: both row-major [8192][512])
__global__ __launch_bounds__(256) void gemm_kernel(
    const unsigned short* __restrict__ Xnb, const unsigned short* __restrict__ Ynb,
    float* __restrict__ rowp, float* __restrict__ colp) {
  __shared__ __align__(16) char sAB[16384];      // sA [0,8K), sB [8K,16K)
  __shared__ float rowpart[2][128];              // [wc][row-in-tile]
  __shared__ float colpart[2][128];              // [wr][col-in-tile]

  const int t    = threadIdx.x;
  const int wv   = t >> 6;
  const int lane = t & 63;
  const int l16  = lane & 15;
  const int lg   = lane >> 4;
  const int wr   = wv >> 1, wc = wv & 1;
  const int br   = blockIdx.y, bc = blockIdx.x;
  const size_t rowA0 = (size_t)br * 128;
  const size_t rowB0 = (size_t)bc * 128;

  f32x4 acc[4][4] = {};

  for (int kt = 0; kt < 16; ++kt) {         // K = 512 = 16 * BK(32)
    const int kb = kt * 32;
    // --- stage A,B tiles (8KB each, 64B rows) via global_load_lds width 16 ---
#pragma unroll
    for (int it = 0; it < 2; ++it) {
      const int obase = it * 4096 + wv * 1024;   // wave-uniform LDS dest
      const int o = obase + lane * 16;           // this lane's 16B slot
      const int r  = o >> 6;                     // tile row (64B per row)
      const int cb = o & 63;                     // byte within row
      async16(sAB + obase,        (const char*)(Xnb + (rowA0 + r) * DD + kb) + cb);
      async16(sAB + 8192 + obase, (const char*)(Ynb + (rowB0 + r) * DD + kb) + cb);
    }
    __syncthreads();   // compiler drains vmcnt before barrier
    // --- MFMA: 4x4 fragments of 16x16x32, one K-slice per tile ---
    bf16x8 af[4], bfv[4];
#pragma unroll
    for (int i = 0; i < 4; ++i) {
      af[i]  = *(const bf16x8*)(sAB + (wr * 64 + i * 16 + l16) * 64 + lg * 16);
      bfv[i] = *(const bf16x8*)(sAB + 8192 + (wc * 64 + i * 16 + l16) * 64 + lg * 16);
    }
#pragma unroll
    for (int i = 0; i < 4; ++i)
#pragma unroll
      for (int j = 0; j < 4; ++j)
        acc[i][j] = __builtin_amdgcn_mfma_f32_16x16x32_bf16(af[i], bfv[j],
                                                            acc[i][j], 0, 0, 0);
    __syncthreads();
  }

  // --- epilogue: E = exp2(S*it - it); reduce rows & cols inside the wave ---
  // D layout (m89-verified): col = l16, row = lg*4 + reg, per 16x16 fragment
  float colacc[4] = {0.f, 0.f, 0.f, 0.f};
#pragma unroll
  for (int i = 0; i < 4; ++i) {
    float rowacc[4] = {0.f, 0.f, 0.f, 0.f};
#pragma unroll
    for (int j = 0; j < 4; ++j)
#pragma unroll
      for (int r = 0; r < 4; ++r) {
        const float e = exp2f(fmaf(acc[i][j][r], INV_T, -INV_T));
        rowacc[r] += e;     // partial over this lane's 4 cols (j loop)
        colacc[j] += e;     // partial over this lane's 16 rows (i,r loops)
      }
#pragma unroll
    for (int r = 0; r < 4; ++r) {     // sum across the 16 lanes sharing a row
      float v = rowacc[r];
      v += __shfl_xor(v, 1); v += __shfl_xor(v, 2);
      v += __shfl_xor(v, 4); v += __shfl_xor(v, 8);
      if (l16 == 0) rowpart[wc][wr * 64 + i * 16 + lg * 4 + r] = v;
    }
  }
#pragma unroll
  for (int j = 0; j < 4; ++j) {       // sum across the 4 lane-groups per col
    float v = colacc[j];
    v += __shfl_xor(v, 16); v += __shfl_xor(v, 32);
    if (lg == 0) colpart[wr][wc * 64 + j * 16 + l16] = v;
  }
  __syncthreads();
  if (t < 128) {
    rowp[(size_t)bc * NB + rowA0 + t] = rowpart[0][t] + rowpart[1][t];
  } else {
    const int c = t - 128;
    colp[(size_t)br * NB + rowB0 + c] = colpart[0][c] + colpart[1][c];
  }
}

// -------- kernel 3: reduce 64 partials per row/col, compute loss --------
__global__ __launch_bounds__(256) void loss_kernel(
    const float* __restrict__ rowp, const float* __restrict__ colp,
    const float* __restrict__ Sv, float* __restrict__ out) {
  __shared__ float wsum[4];
  const int i = blockIdx.x * 256 + threadIdx.x;   // grid 32 -> all 8192 rows
  float rs = 0.f, cs = 0.f;
  for (int b = 0; b < 64; ++b) {
    rs += rowp[(size_t)b * NB + i];
    cs += colp[(size_t)b * NB + i];
  }
  float v = 2.f * Sv[i] - logf(rs) - logf(cs);    // logit_i
#pragma unroll
  for (int m = 1; m < 64; m <<= 1) v += __shfl_xor(v, m);
  if ((threadIdx.x & 63) == 0) wsum[threadIdx.x >> 6] = v;
  __syncthreads();
  if (threadIdx.x == 0) {
    const float s = wsum[0] + wsum[1] + wsum[2] + wsum[3];
    atomicAdd(out, s * (-1.0f / (2.0f * NB)));    // loss = -mean(logits)/2
  }
}

extern "C" void kernel_launch(void* const* d_in, const int* in_sizes, int n_in,
                              void* d_out, int out_size, void* d_ws, size_t ws_size,
                              hipStream_t stream) {
  const float* X = (const float*)d_in[0];   // image_features
  const float* Y = (const float*)d_in[1];   // text_features
  char* ws = (char*)d_ws;
  // workspace layout (21.0 MB total)
  unsigned short* Xnb = (unsigned short*)(ws);                       // 8 MB
  unsigned short* Ynb = (unsigned short*)(ws + 8388608);             // 8 MB
  float* Sv   = (float*)(ws + 16777216);                             // 32 KB
  float* rowp = (float*)(ws + 16777216 + 32768);                     // 2 MB
  float* colp = (float*)(ws + 16777216 + 32768 + 2097152);           // 2 MB
  float* out  = (float*)d_out;

  hipMemsetAsync(d_out, 0, sizeof(float), stream);  // d_out is 0xAA-poisoned
  norm_kernel<<<NB / 4, 256, 0, stream>>>(X, Y, Xnb, Ynb, Sv);
  gemm_kernel<<<dim3(64, 64), 256, 0, stream>>>(Xnb, Ynb, rowp, colp);
  loss_kernel<<<32, 256, 0, stream>>>(rowp, colp, Sv, out);
}

// Round 4
// 182.090 us; speedup vs baseline: 1.0739x; 1.0036x over previous
//
#include <hip/hip_runtime.h>

// Problem constants (fixed by reference setup_inputs)
#define NB 8192      // rows of X and Y
#define DD 512       // feature dim
#define INV_T 20.609929155556618f   // (float)(log2(e)/0.07)

typedef short bf16x8 __attribute__((ext_vector_type(8)));  // 8 bf16 in 4 VGPRs
typedef float f32x4  __attribute__((ext_vector_type(4)));

// round-to-nearest-even fp32 -> bf16
__device__ static inline unsigned short f2bf(float f) {
  unsigned int u = __float_as_uint(f);
  u += 0x7fff + ((u >> 16) & 1);
  return (unsigned short)(u >> 16);
}

// async global->LDS, 16B per lane; lds base wave-uniform, HW adds lane*16
__device__ static inline void async16(const void* lds, const void* g) {
  __builtin_amdgcn_global_load_lds(
      (const __attribute__((address_space(1))) unsigned int*)g,
      (__attribute__((address_space(3))) unsigned int*)lds, 16, 0, 0);
}

// -------- kernel 1: fused L2-normalize (fp32->bf16) + diagonal Sv --------
__global__ __launch_bounds__(256) void norm_kernel(
    const float* __restrict__ X, const float* __restrict__ Y,
    unsigned short* __restrict__ Xnb, unsigned short* __restrict__ Ynb,
    float* __restrict__ Sv) {
  const int wv   = threadIdx.x >> 6;
  const int lane = threadIdx.x & 63;
  const int row  = blockIdx.x * 4 + wv;
  const float4* x4 = (const float4*)(X + (size_t)row * DD);
  const float4* y4 = (const float4*)(Y + (size_t)row * DD);
  float4 xa = x4[lane * 2], xb = x4[lane * 2 + 1];
  float4 ya = y4[lane * 2], yb = y4[lane * 2 + 1];
  float xs[8] = {xa.x, xa.y, xa.z, xa.w, xb.x, xb.y, xb.z, xb.w};
  float ys[8] = {ya.x, ya.y, ya.z, ya.w, yb.x, yb.y, yb.z, yb.w};
  float ssx = 0.f, ssy = 0.f, sxy = 0.f;
#pragma unroll
  for (int k = 0; k < 8; ++k) {
    ssx += xs[k] * xs[k];
    ssy += ys[k] * ys[k];
    sxy += xs[k] * ys[k];
  }
#pragma unroll
  for (int m = 1; m < 64; m <<= 1) {
    ssx += __shfl_xor(ssx, m);
    ssy += __shfl_xor(ssy, m);
    sxy += __shfl_xor(sxy, m);
  }
  const float rnx = 1.0f / sqrtf(ssx);
  const float rny = 1.0f / sqrtf(ssy);
  unsigned short ox[8], oy[8];
#pragma unroll
  for (int k = 0; k < 8; ++k) {
    ox[k] = f2bf(xs[k] * rnx);
    oy[k] = f2bf(ys[k] * rny);
  }
  *(uint4*)(Xnb + (size_t)row * DD + lane * 8) = *(const uint4*)ox;
  *(uint4*)(Ynb + (size_t)row * DD + lane * 8) = *(const uint4*)oy;
  if (lane == 0) Sv[row] = sxy * rnx * rny * INV_T - INV_T;
}

// -------- kernel 2: 256x256 tile, 8-wave rotated-phase pipelined MFMA ------
// LDS: 2 buffers x (A[256][64] + B[256][64]) bf16 = 131072 B, + 6 KB partials.
// Swizzle (T2): phys = L ^ ((row&7)<<4); staged via inverse-swizzled global src
// (linear global_load_lds dest), read back with the same XOR (rule #21).
// Phase schedule per K-tile t (buf base = (t&1)*64KB, other = ^64KB):
//  P1: read bf(n1) | stage A(t+1)->other | Q(m0,n0) | barrier
//  P2: read af(m1) | stage B(t+1)->other | Q(m0,n1) | barrier
//  P3: Q(m1,n0) | vmcnt(0) (stages issued >=1 phase ago) | barrier(other ready)
//  P4: read af'(m0)+bf'(n0) from other | Q(m1,n1) | barrier

#define STAGE_HALF(SRC, ROW0, LBASE, T) do {                                   \
  _Pragma("unroll") for (int s_ = 0; s_ < 2; ++s_) {                           \
    const int Pl_ = s_ * 8192 + tid * 16;                                      \
    const int L_  = Pl_ ^ (((Pl_ >> 7) & 7) << 4);                             \
    async16(sT + (LBASE) + s_ * 8192 + wv * 1024,                              \
            (const char*)(SRC) + (size_t)((ROW0) + (L_ >> 7)) * 1024           \
              + (T) * 128 + (L_ & 127));                                       \
  } } while (0)

#define STAGE_A(B_, T_) do {                                                   \
    STAGE_HALF(Xnb, br * 256,       (B_),         (T_));                       \
    STAGE_HALF(Xnb, br * 256 + 128, (B_) + 16384, (T_)); } while (0)
#define STAGE_B(B_, T_) do {                                                   \
    STAGE_HALF(Ynb, bc * 256,       (B_) + 32768, (T_));                       \
    STAGE_HALF(Ynb, bc * 256 + 128, (B_) + 49152, (T_)); } while (0)

#define READ_A(B_, MH) do {                                                    \
  _Pragma("unroll") for (int ks_ = 0; ks_ < 2; ++ks_)                          \
  _Pragma("unroll") for (int i_ = 0; i_ < 4; ++i_)                             \
    af[MH][ks_][i_] = *(const bf16x8*)(sT +                                    \
      (((B_) + aoffL + (MH) * 8192 + i_ * 2048 + ks_ * 64) ^ aswz));           \
  } while (0)

#define READ_B(B_, J0) do {                                                    \
  _Pragma("unroll") for (int ks_ = 0; ks_ < 2; ++ks_)                          \
  _Pragma("unroll") for (int j_ = 0; j_ < 2; ++j_)                             \
    bfr[ks_][(J0) + j_] = *(const bf16x8*)(sT +                                \
      (((B_) + boffL + ((J0) + j_) * 2048 + ks_ * 64) ^ aswz));                \
  } while (0)

#define QUAD(MH, NH) do {                                                      \
  __builtin_amdgcn_s_setprio(1);                                               \
  _Pragma("unroll") for (int ks_ = 0; ks_ < 2; ++ks_)                          \
  _Pragma("unroll") for (int i_ = 0; i_ < 4; ++i_)                             \
  _Pragma("unroll") for (int j_ = 0; j_ < 2; ++j_)                             \
    acc[(MH) * 4 + i_][(NH) * 2 + j_] =                                        \
      __builtin_amdgcn_mfma_f32_16x16x32_bf16(                                 \
        af[MH][ks_][i_], bfr[ks_][(NH) * 2 + j_],                              \
        acc[(MH) * 4 + i_][(NH) * 2 + j_], 0, 0, 0);                           \
  __builtin_amdgcn_s_setprio(0);                                               \
  } while (0)

__global__ __launch_bounds__(512, 1) void gemm_kernel(
    const unsigned short* __restrict__ Xnb, const unsigned short* __restrict__ Ynb,
    float* __restrict__ rowp, float* __restrict__ colp) {
  extern __shared__ __align__(16) char sT[];
  float* rp = (float*)(sT + 131072);          // [4][256]
  float* cp = (float*)(sT + 131072 + 4096);   // [2][256]

  const int tid  = threadIdx.x;
  const int wv   = tid >> 6;
  const int lane = tid & 63;
  const int l16  = lane & 15;
  const int lg   = lane >> 4;
  const int wr   = wv >> 2, wc = wv & 3;      // 2 x 4 wave grid
  const int br   = blockIdx.y, bc = blockIdx.x;

  const int aswz  = (l16 & 7) << 4;                       // row&7 == l16&7
  const int aoffL = (wr * 128 + l16) * 128 + lg * 16;     // A frag base (conceptual)
  const int boffL = 32768 + (wc * 64 + l16) * 128 + lg * 16;

  f32x4  acc[8][4] = {};
  bf16x8 af[2][2][4];   // [m-half][kslice][frag]
  bf16x8 bfr[2][4];     // [kslice][col-frag]

  // prologue: stage tile 0 into buf0, drain, read Q(m0,n0) frags
  STAGE_A(0, 0);
  STAGE_B(0, 0);
  asm volatile("s_waitcnt vmcnt(0)" ::: "memory");
  __builtin_amdgcn_s_barrier();
  asm volatile("" ::: "memory");
  READ_A(0, 0);
  READ_B(0, 0);

  for (int t = 0; t < 8; ++t) {               // K = 512 = 8 x BK(64)
    const int base  = (t & 1) << 16;
    const int other = base ^ (1 << 16);
    const bool pf   = (t < 7);
    // ---- P1 ----
    READ_B(base, 2);
    if (pf) STAGE_A(other, t + 1);
    __builtin_amdgcn_s_barrier();
    QUAD(0, 0);
    __builtin_amdgcn_s_barrier();
    // ---- P2 ----
    READ_A(base, 1);
    if (pf) STAGE_B(other, t + 1);
    __builtin_amdgcn_s_barrier();
    QUAD(0, 1);
    __builtin_amdgcn_s_barrier();
    // ---- P3 ----
    QUAD(1, 0);
    if (pf) asm volatile("s_waitcnt vmcnt(0)" ::: "memory");
    asm volatile("s_barrier" ::: "memory");   // after this, `other` holds t+1
    // ---- P4 ----
    if (pf) {
      READ_A(other, 0);
      READ_B(other, 0);
    }
    QUAD(1, 1);
    __builtin_amdgcn_s_barrier();
  }

  // ---- epilogue: E = exp2(S*it - it); row/col partial sums ----
  // D frag layout (m89): col = l16, row = lg*4 + reg within each 16x16
  float cacc[4] = {0.f, 0.f, 0.f, 0.f};
#pragma unroll
  for (int I = 0; I < 8; ++I) {
    float racc[4] = {0.f, 0.f, 0.f, 0.f};
#pragma unroll
    for (int J = 0; J < 4; ++J)
#pragma unroll
      for (int r = 0; r < 4; ++r) {
        const float e = exp2f(fmaf(acc[I][J][r], INV_T, -INV_T));
        racc[r] += e;
        cacc[J] += e;
      }
#pragma unroll
    for (int r = 0; r < 4; ++r) {
      float v = racc[r];
      v += __shfl_xor(v, 1); v += __shfl_xor(v, 2);
      v += __shfl_xor(v, 4); v += __shfl_xor(v, 8);
      if (l16 == 0) rp[wc * 256 + wr * 128 + I * 16 + lg * 4 + r] = v;
    }
  }
#pragma unroll
  for (int J = 0; J < 4; ++J) {
    float v = cacc[J];
    v += __shfl_xor(v, 16); v += __shfl_xor(v, 32);
    if (lg == 0) cp[wr * 256 + wc * 64 + J * 16 + l16] = v;
  }
  __syncthreads();
  if (tid < 256) {
    rowp[(size_t)bc * NB + br * 256 + tid] =
        rp[tid] + rp[256 + tid] + rp[512 + tid] + rp[768 + tid];
  } else {
    const int c = tid - 256;
    colp[(size_t)br * NB + bc * 256 + c] = cp[c] + cp[256 + c];
  }
}

// -------- kernel 3: reduce 32 partials per row/col, compute loss --------
__global__ __launch_bounds__(256) void loss_kernel(
    const float* __restrict__ rowp, const float* __restrict__ colp,
    const float* __restrict__ Sv, float* __restrict__ out) {
  __shared__ float wsum[4];
  const int i = blockIdx.x * 256 + threadIdx.x;
  float rs = 0.f, cs = 0.f;
  for (int b = 0; b < 32; ++b) {
    rs += rowp[(size_t)b * NB + i];
    cs += colp[(size_t)b * NB + i];
  }
  float v = 2.f * Sv[i] - logf(rs) - logf(cs);
#pragma unroll
  for (int m = 1; m < 64; m <<= 1) v += __shfl_xor(v, m);
  if ((threadIdx.x & 63) == 0) wsum[threadIdx.x >> 6] = v;
  __syncthreads();
  if (threadIdx.x == 0) {
    const float s = wsum[0] + wsum[1] + wsum[2] + wsum[3];
    atomicAdd(out, s * (-1.0f / (2.0f * NB)));
  }
}

extern "C" void kernel_launch(void* const* d_in, const int* in_sizes, int n_in,
                              void* d_out, int out_size, void* d_ws, size_t ws_size,
                              hipStream_t stream) {
  const float* X = (const float*)d_in[0];   // image_features
  const float* Y = (const float*)d_in[1];   // text_features
  char* ws = (char*)d_ws;
  // workspace layout (~18 MB)
  unsigned short* Xnb = (unsigned short*)(ws);                       // 8 MB
  unsigned short* Ynb = (unsigned short*)(ws + 8388608);             // 8 MB
  float* Sv   = (float*)(ws + 16777216);                             // 32 KB
  float* rowp = (float*)(ws + 16777216 + 32768);                     // 1 MB
  float* colp = (float*)(ws + 16777216 + 32768 + 1048576);           // 1 MB
  float* out  = (float*)d_out;

  // allow 137 KB dynamic LDS (idempotent; ignore result)
  (void)hipFuncSetAttribute((const void*)gemm_kernel,
                            hipFuncAttributeMaxDynamicSharedMemorySize,
                            131072 + 6144);

  hipMemsetAsync(d_out, 0, sizeof(float), stream);
  norm_kernel<<<NB / 4, 256, 0, stream>>>(X, Y, Xnb, Ynb, Sv);
  gemm_kernel<<<dim3(32, 32), 512, 131072 + 6144, stream>>>(Xnb, Ynb, rowp, colp);
  loss_kernel<<<32, 256, 0, stream>>>(rowp, colp, Sv, out);
}

// Round 8
// 167.527 us; speedup vs baseline: 1.1672x; 1.0869x over previous
//
#include <hip/hip_runtime.h>

// Problem constants (fixed by reference setup_inputs)
#define NB 8192      // rows of X and Y
#define DD 512       // feature dim
#define INV_T 20.609929155556618f   // (float)(log2(e)/0.07)

typedef short bf16x8 __attribute__((ext_vector_type(8)));  // 8 bf16 in 4 VGPRs
typedef float f32x4  __attribute__((ext_vector_type(4)));

// round-to-nearest-even fp32 -> bf16
__device__ static inline unsigned short f2bf(float f) {
  unsigned int u = __float_as_uint(f);
  u += 0x7fff + ((u >> 16) & 1);
  return (unsigned short)(u >> 16);
}

// async global->LDS, 16B per lane; lds base wave-uniform, HW adds lane*16
__device__ static inline void async16(const void* lds, const void* g) {
  __builtin_amdgcn_global_load_lds(
      (const __attribute__((address_space(1))) unsigned int*)g,
      (__attribute__((address_space(3))) unsigned int*)lds, 16, 0, 0);
}

// -------- kernel 1: fused L2-normalize (fp32->bf16) + diagonal Sv --------
// one wave per row; loads x4[lane] (elems 4l..4l+3) and x4[lane+64]
// (elems 256+4l..); stores mirror that layout with two uint2 halves.
__global__ __launch_bounds__(256) void norm_kernel2(
    const float* __restrict__ X, const float* __restrict__ Y,
    unsigned short* __restrict__ Xnb, unsigned short* __restrict__ Ynb,
    float* __restrict__ Sv) {
  const int wv   = threadIdx.x >> 6;
  const int lane = threadIdx.x & 63;
  const int row  = blockIdx.x * 4 + wv;
  const float4* x4 = (const float4*)(X + (size_t)row * DD);
  const float4* y4 = (const float4*)(Y + (size_t)row * DD);
  float4 xa = x4[lane], xb = x4[lane + 64];
  float4 ya = y4[lane], yb = y4[lane + 64];
  float xs[8] = {xa.x, xa.y, xa.z, xa.w, xb.x, xb.y, xb.z, xb.w};
  float ys[8] = {ya.x, ya.y, ya.z, ya.w, yb.x, yb.y, yb.z, yb.w};
  float ssx = 0.f, ssy = 0.f, sxy = 0.f;
#pragma unroll
  for (int k = 0; k < 8; ++k) {
    ssx += xs[k] * xs[k];
    ssy += ys[k] * ys[k];
    sxy += xs[k] * ys[k];
  }
#pragma unroll
  for (int m = 1; m < 64; m <<= 1) {
    ssx += __shfl_xor(ssx, m);
    ssy += __shfl_xor(ssy, m);
    sxy += __shfl_xor(sxy, m);
  }
  const float rnx = 1.0f / sqrtf(ssx);
  const float rny = 1.0f / sqrtf(ssy);
  unsigned short ox[8], oy[8];
#pragma unroll
  for (int k = 0; k < 8; ++k) {
    ox[k] = f2bf(xs[k] * rnx);
    oy[k] = f2bf(ys[k] * rny);
  }
  *(uint2*)(Xnb + (size_t)row * DD + lane * 4)       = *(const uint2*)&ox[0];
  *(uint2*)(Xnb + (size_t)row * DD + 256 + lane * 4) = *(const uint2*)&ox[4];
  *(uint2*)(Ynb + (size_t)row * DD + lane * 4)       = *(const uint2*)&oy[0];
  *(uint2*)(Ynb + (size_t)row * DD + 256 + lane * 4) = *(const uint2*)&oy[4];
  if (lane == 0) Sv[row] = sxy * rnx * rny * INV_T - INV_T;
}

// -------- kernel 2: 256x256 tile, 8-wave pipelined MFMA, XCD-clustered ------
// LDS: 2 buffers x (A[256][64] + B[256][64]) bf16 = 131072 B (partials reuse it).
// Swizzle (T2): phys = logical ^ ((row&7)<<4), staged via pre-swizzled global
// source + linear global_load_lds dest (rule #21) — byte-identical to the
// round-4 verified layout, re-expressed with hoisted bases.

#define STAGE_A(BUF, T) do {                                                   \
  _Pragma("unroll") for (int h_ = 0; h_ < 2; ++h_) {                           \
    async16(sT + (BUF) + h_ * 16384 + wv * 1024,                               \
            Ab + h_ * 131072 + (T) * 128 + g0);                                \
    async16(sT + (BUF) + h_ * 16384 + 8192 + wv * 1024,                        \
            Ab + h_ * 131072 + (T) * 128 + g1);                                \
  } } while (0)

#define STAGE_B(BUF, T) do {                                                   \
  _Pragma("unroll") for (int h_ = 0; h_ < 2; ++h_) {                           \
    async16(sT + (BUF) + 32768 + h_ * 16384 + wv * 1024,                       \
            Bb + h_ * 131072 + (T) * 128 + g0);                                \
    async16(sT + (BUF) + 32768 + h_ * 16384 + 8192 + wv * 1024,                \
            Bb + h_ * 131072 + (T) * 128 + g1);                                \
  } } while (0)

#define READ_A(BUF, MH) do {                                                   \
  _Pragma("unroll") for (int ks_ = 0; ks_ < 2; ++ks_)                          \
  _Pragma("unroll") for (int i_ = 0; i_ < 4; ++i_)                             \
    af[MH][ks_][i_] = *(const bf16x8*)(sT + (BUF) + raB[ks_]                   \
                                       + (MH) * 8192 + i_ * 2048);             \
  } while (0)

#define READ_B(BUF, J0) do {                                                   \
  _Pragma("unroll") for (int ks_ = 0; ks_ < 2; ++ks_)                          \
  _Pragma("unroll") for (int j_ = 0; j_ < 2; ++j_)                             \
    bfr[ks_][(J0) + j_] = *(const bf16x8*)(sT + (BUF) + rbB[ks_]               \
                                           + ((J0) + j_) * 2048);              \
  } while (0)

#define QUAD(MH, NH) do {                                                      \
  __builtin_amdgcn_s_setprio(1);                                               \
  _Pragma("unroll") for (int ks_ = 0; ks_ < 2; ++ks_)                          \
  _Pragma("unroll") for (int i_ = 0; i_ < 4; ++i_)                             \
  _Pragma("unroll") for (int j_ = 0; j_ < 2; ++j_)                             \
    acc[(MH) * 4 + i_][(NH) * 2 + j_] =                                        \
      __builtin_amdgcn_mfma_f32_16x16x32_bf16(                                 \
        af[MH][ks_][i_], bfr[ks_][(NH) * 2 + j_],                              \
        acc[(MH) * 4 + i_][(NH) * 2 + j_], 0, 0, 0);                           \
  __builtin_amdgcn_s_setprio(0);                                               \
  } while (0)

__global__ __launch_bounds__(512, 1) void gemm_kernel(
    const unsigned short* __restrict__ Xnb, const unsigned short* __restrict__ Ynb,
    float* __restrict__ rowp, float* __restrict__ colp) {
  extern __shared__ __align__(16) char sT[];

  const int tid  = threadIdx.x;
  const int wv   = tid >> 6;
  const int lane = tid & 63;
  const int l16  = lane & 15;
  const int lg   = lane >> 4;
  const int wr   = wv >> 2, wc = wv & 3;      // 2 x 4 wave grid

  // T1: XCD cluster swizzle. 1024 blocks, 8 XCDs; each XCD round = 8x4 tile
  // cluster (2MB A + 1MB B < 4MB L2); B band persists across the XCD's rounds.
  const int bid = blockIdx.x;
  const int xcd = bid & 7;
  const int idx = bid >> 3;
  const int w   = idx & 31;
  const int br  = (idx >> 5) * 8 + (w & 7);
  const int bc  = xcd * 4 + (w >> 3);

  // hoisted per-lane stage-source offsets (pre-swizzled, round-4-identical)
  const int Pl0 = tid * 16;
  const int L0  = Pl0 ^ (((Pl0 >> 7) & 7) << 4);
  const int Pl1 = 8192 + tid * 16;
  const int L1  = Pl1 ^ (((Pl1 >> 7) & 7) << 4);
  const int g0  = (L0 >> 7) * 1024 + (L0 & 127);
  const int g1  = (L1 >> 7) * 1024 + (L1 & 127);
  const char* Ab = (const char*)Xnb + (size_t)br * 262144;  // 256 rows x 1KB
  const char* Bb = (const char*)Ynb + (size_t)bc * 262144;

  // hoisted swizzled LDS read bases (ks folded into the XOR: bit6 aliases)
  const int aswz = (l16 & 7) << 4;
  const int raB[2] = { (wr * 128 + l16) * 128 + ((lg * 16)      ^ aswz),
                       (wr * 128 + l16) * 128 + ((lg * 16 + 64) ^ aswz) };
  const int rbB[2] = { 32768 + (wc * 64 + l16) * 128 + ((lg * 16)      ^ aswz),
                       32768 + (wc * 64 + l16) * 128 + ((lg * 16 + 64) ^ aswz) };

  f32x4  acc[8][4] = {};
  bf16x8 af[2][2][4];   // [m-half][kslice][frag]
  bf16x8 bfr[2][4];     // [kslice][col-frag]

  // prologue: stage tile 0 into buf0, drain, prefetch first fragments
  STAGE_A(0, 0);
  STAGE_B(0, 0);
  asm volatile("s_waitcnt vmcnt(0)" ::: "memory");
  __builtin_amdgcn_s_barrier();
  asm volatile("" ::: "memory");
  READ_A(0, 0);
  READ_B(0, 0);

  for (int t = 0; t < 8; ++t) {               // K = 512 = 8 x BK(64)
    const int base  = (t & 1) << 16;
    const int other = base ^ (1 << 16);
    const bool pf   = (t < 7);
    // ---- P1 ----
    READ_B(base, 2);
    if (pf) STAGE_A(other, t + 1);
    __builtin_amdgcn_s_barrier();
    QUAD(0, 0);
    __builtin_amdgcn_s_barrier();
    // ---- P2 ----
    READ_A(base, 1);
    if (pf) STAGE_B(other, t + 1);
    __builtin_amdgcn_s_barrier();
    QUAD(0, 1);
    __builtin_amdgcn_s_barrier();
    // ---- P3: 32 MFMA cover the stage drain; single stall point per tile ----
    QUAD(1, 0);
    QUAD(1, 1);
    if (pf) asm volatile("s_waitcnt vmcnt(0)" ::: "memory");
    __builtin_amdgcn_s_barrier();
    asm volatile("" ::: "memory");
    if (pf) {
      READ_A(other, 0);
      READ_B(other, 0);
    }
  }

  // ---- epilogue: E = exp2(S*it - it); row/col partial sums (reuse sT) ----
  __syncthreads();
  float* rp = (float*)sT;            // [4][256]
  float* cp = (float*)(sT + 4096);   // [2][256]
  // D frag layout (m89): col = l16, row = lg*4 + reg within each 16x16
  float cacc[4] = {0.f, 0.f, 0.f, 0.f};
#pragma unroll
  for (int I = 0; I < 8; ++I) {
    float racc[4] = {0.f, 0.f, 0.f, 0.f};
#pragma unroll
    for (int J = 0; J < 4; ++J)
#pragma unroll
      for (int r = 0; r < 4; ++r) {
        const float e = exp2f(fmaf(acc[I][J][r], INV_T, -INV_T));
        racc[r] += e;
        cacc[J] += e;
      }
#pragma unroll
    for (int r = 0; r < 4; ++r) {
      float v = racc[r];
      v += __shfl_xor(v, 1); v += __shfl_xor(v, 2);
      v += __shfl_xor(v, 4); v += __shfl_xor(v, 8);
      if (l16 == 0) rp[wc * 256 + wr * 128 + I * 16 + lg * 4 + r] = v;
    }
  }
#pragma unroll
  for (int J = 0; J < 4; ++J) {
    float v = cacc[J];
    v += __shfl_xor(v, 16); v += __shfl_xor(v, 32);
    if (lg == 0) cp[wr * 256 + wc * 64 + J * 16 + l16] = v;
  }
  __syncthreads();
  if (tid < 256) {
    rowp[(size_t)bc * NB + br * 256 + tid] =
        rp[tid] + rp[256 + tid] + rp[512 + tid] + rp[768 + tid];
  } else {
    const int c = tid - 256;
    colp[(size_t)br * NB + bc * 256 + c] = cp[c] + cp[256 + c];
  }
}

// -------- kernel 3: reduce 32 partials per row/col, compute loss --------
__global__ __launch_bounds__(256) void loss_kernel(
    const float* __restrict__ rowp, const float* __restrict__ colp,
    const float* __restrict__ Sv, float* __restrict__ out) {
  __shared__ float wsum[4];
  const int i = blockIdx.x * 256 + threadIdx.x;
  float rs = 0.f, cs = 0.f;
#pragma unroll 4
  for (int b = 0; b < 32; ++b) {
    rs += rowp[(size_t)b * NB + i];
    cs += colp[(size_t)b * NB + i];
  }
  float v = 2.f * Sv[i] - logf(rs) - logf(cs);
#pragma unroll
  for (int m = 1; m < 64; m <<= 1) v += __shfl_xor(v, m);
  if ((threadIdx.x & 63) == 0) wsum[threadIdx.x >> 6] = v;
  __syncthreads();
  if (threadIdx.x == 0) {
    const float s = wsum[0] + wsum[1] + wsum[2] + wsum[3];
    atomicAdd(out, s * (-1.0f / (2.0f * NB)));
  }
}

extern "C" void kernel_launch(void* const* d_in, const int* in_sizes, int n_in,
                              void* d_out, int out_size, void* d_ws, size_t ws_size,
                              hipStream_t stream) {
  const float* X = (const float*)d_in[0];   // image_features
  const float* Y = (const float*)d_in[1];   // text_features
  char* ws = (char*)d_ws;
  // workspace layout (~19 MB)
  unsigned short* Xnb = (unsigned short*)(ws);                       // 8 MB
  unsigned short* Ynb = (unsigned short*)(ws + 8388608);             // 8 MB
  float* Sv   = (float*)(ws + 16777216);                             // 32 KB
  float* rowp = (float*)(ws + 16777216 + 32768);                     // 1 MB
  float* colp = (float*)(ws + 16777216 + 32768 + 1048576);           // 1 MB
  float* out  = (float*)d_out;

  (void)hipFuncSetAttribute((const void*)gemm_kernel,
                            hipFuncAttributeMaxDynamicSharedMemorySize,
                            131072);

  hipMemsetAsync(d_out, 0, sizeof(float), stream);
  norm_kernel2<<<NB / 4, 256, 0, stream>>>(X, Y, Xnb, Ynb, Sv);
  gemm_kernel<<<1024, 512, 131072, stream>>>(Xnb, Ynb, rowp, colp);
  loss_kernel<<<32, 256, 0, stream>>>(rowp, colp, Sv, out);
}

// Round 9
// 162.419 us; speedup vs baseline: 1.2039x; 1.0315x over previous
//
#include <hip/hip_runtime.h>

// Problem constants (fixed by reference setup_inputs)
#define NB 8192      // rows of X and Y
#define DD 512       // feature dim
#define INV_T 20.609929155556618f   // (float)(log2(e)/0.07)

typedef short bf16x8 __attribute__((ext_vector_type(8)));  // 8 bf16 in 4 VGPRs
typedef float f32x4  __attribute__((ext_vector_type(4)));

// round-to-nearest-even fp32 -> bf16
__device__ static inline unsigned short f2bf(float f) {
  unsigned int u = __float_as_uint(f);
  u += 0x7fff + ((u >> 16) & 1);
  return (unsigned short)(u >> 16);
}

// async global->LDS, 16B per lane; lds base wave-uniform, HW adds lane*16
__device__ static inline void async16(const void* lds, const void* g) {
  __builtin_amdgcn_global_load_lds(
      (const __attribute__((address_space(1))) unsigned int*)g,
      (__attribute__((address_space(3))) unsigned int*)lds, 16, 0, 0);
}

// -------- kernel 1: fused L2-normalize (fp32->bf16) + diagonal Sv --------
__global__ __launch_bounds__(256) void norm_kernel2(
    const float* __restrict__ X, const float* __restrict__ Y,
    unsigned short* __restrict__ Xnb, unsigned short* __restrict__ Ynb,
    float* __restrict__ Sv) {
  const int wv   = threadIdx.x >> 6;
  const int lane = threadIdx.x & 63;
  const int row  = blockIdx.x * 4 + wv;
  const float4* x4 = (const float4*)(X + (size_t)row * DD);
  const float4* y4 = (const float4*)(Y + (size_t)row * DD);
  float4 xa = x4[lane], xb = x4[lane + 64];
  float4 ya = y4[lane], yb = y4[lane + 64];
  float xs[8] = {xa.x, xa.y, xa.z, xa.w, xb.x, xb.y, xb.z, xb.w};
  float ys[8] = {ya.x, ya.y, ya.z, ya.w, yb.x, yb.y, yb.z, yb.w};
  float ssx = 0.f, ssy = 0.f, sxy = 0.f;
#pragma unroll
  for (int k = 0; k < 8; ++k) {
    ssx += xs[k] * xs[k];
    ssy += ys[k] * ys[k];
    sxy += xs[k] * ys[k];
  }
#pragma unroll
  for (int m = 1; m < 64; m <<= 1) {
    ssx += __shfl_xor(ssx, m);
    ssy += __shfl_xor(ssy, m);
    sxy += __shfl_xor(sxy, m);
  }
  const float rnx = 1.0f / sqrtf(ssx);
  const float rny = 1.0f / sqrtf(ssy);
  unsigned short ox[8], oy[8];
#pragma unroll
  for (int k = 0; k < 8; ++k) {
    ox[k] = f2bf(xs[k] * rnx);
    oy[k] = f2bf(ys[k] * rny);
  }
  *(uint2*)(Xnb + (size_t)row * DD + lane * 4)       = *(const uint2*)&ox[0];
  *(uint2*)(Xnb + (size_t)row * DD + 256 + lane * 4) = *(const uint2*)&ox[4];
  *(uint2*)(Ynb + (size_t)row * DD + lane * 4)       = *(const uint2*)&oy[0];
  *(uint2*)(Ynb + (size_t)row * DD + 256 + lane * 4) = *(const uint2*)&oy[4];
  if (lane == 0) Sv[row] = sxy * rnx * rny * INV_T - INV_T;
}

// -------- kernel 2: 256x256 tile, counted-vmcnt depth-2 pipeline -----------
// LDS: 2 buffers x (A[256][64] + B[256][64]) bf16 = 131072 B.
// Swizzle (T2): phys = logical ^ ((row&7)<<4) via pre-swizzled global source.
// Steady state per K-tile t (cur=t&1):
//  Ph1: ds_read af[1],bfr[23] <- cur | Q(0,0) | lgkm(0) | bar
//  Ph2: stage A(t+2) -> cur (4 loads)  | Q(0,1) | bar
//  Ph3: stage B(t+2) -> cur (4 loads)  | Q(1,0) | bar
//  Ph4: vmcnt(8) [t+1 landed, t+2 in flight] | bar |
//       ds_read af[0],bfr[01] <- other | Q(1,1) | bar
// 16 loads in flight steady; vmcnt never drains to 0 until the tail (t==6).

#define STAGE_A(BUF, T) do {                                                   \
  _Pragma("unroll") for (int h_ = 0; h_ < 2; ++h_) {                           \
    async16(sT + (BUF) + h_ * 16384 + wv * 1024,                               \
            Ab + h_ * 131072 + (T) * 128 + g0);                                \
    async16(sT + (BUF) + h_ * 16384 + 8192 + wv * 1024,                        \
            Ab + h_ * 131072 + (T) * 128 + g1);                                \
  } } while (0)

#define STAGE_B(BUF, T) do {                                                   \
  _Pragma("unroll") for (int h_ = 0; h_ < 2; ++h_) {                           \
    async16(sT + (BUF) + 32768 + h_ * 16384 + wv * 1024,                       \
            Bb + h_ * 131072 + (T) * 128 + g0);                                \
    async16(sT + (BUF) + 32768 + h_ * 16384 + 8192 + wv * 1024,                \
            Bb + h_ * 131072 + (T) * 128 + g1);                                \
  } } while (0)

#define READ_A(BUF, MH) do {                                                   \
  _Pragma("unroll") for (int ks_ = 0; ks_ < 2; ++ks_)                          \
  _Pragma("unroll") for (int i_ = 0; i_ < 4; ++i_)                             \
    af[MH][ks_][i_] = *(const bf16x8*)(sT + (BUF) + raB[ks_]                   \
                                       + (MH) * 8192 + i_ * 2048);             \
  } while (0)

#define READ_B(BUF, J0) do {                                                   \
  _Pragma("unroll") for (int ks_ = 0; ks_ < 2; ++ks_)                          \
  _Pragma("unroll") for (int j_ = 0; j_ < 2; ++j_)                             \
    bfr[ks_][(J0) + j_] = *(const bf16x8*)(sT + (BUF) + rbB[ks_]               \
                                           + ((J0) + j_) * 2048);              \
  } while (0)

#define QUAD(MH, NH) do {                                                      \
  __builtin_amdgcn_s_setprio(1);                                               \
  _Pragma("unroll") for (int ks_ = 0; ks_ < 2; ++ks_)                          \
  _Pragma("unroll") for (int i_ = 0; i_ < 4; ++i_)                             \
  _Pragma("unroll") for (int j_ = 0; j_ < 2; ++j_)                             \
    acc[(MH) * 4 + i_][(NH) * 2 + j_] =                                        \
      __builtin_amdgcn_mfma_f32_16x16x32_bf16(                                 \
        af[MH][ks_][i_], bfr[ks_][(NH) * 2 + j_],                              \
        acc[(MH) * 4 + i_][(NH) * 2 + j_], 0, 0, 0);                           \
  __builtin_amdgcn_s_setprio(0);                                               \
  } while (0)

__global__ __launch_bounds__(512, 1) void gemm_kernel(
    const unsigned short* __restrict__ Xnb, const unsigned short* __restrict__ Ynb,
    float* __restrict__ rowp, float* __restrict__ colp) {
  extern __shared__ __align__(16) char sT[];

  const int tid  = threadIdx.x;
  const int wv   = tid >> 6;
  const int lane = tid & 63;
  const int l16  = lane & 15;
  const int lg   = lane >> 4;
  const int wr   = wv >> 2, wc = wv & 3;      // 2 x 4 wave grid

  // T1: XCD cluster swizzle (kept from round 8).
  const int bid = blockIdx.x;
  const int xcd = bid & 7;
  const int idx = bid >> 3;
  const int w   = idx & 31;
  const int br  = (idx >> 5) * 8 + (w & 7);
  const int bc  = xcd * 4 + (w >> 3);

  // hoisted per-lane stage-source offsets (pre-swizzled)
  const int Pl0 = tid * 16;
  const int L0  = Pl0 ^ (((Pl0 >> 7) & 7) << 4);
  const int Pl1 = 8192 + tid * 16;
  const int L1  = Pl1 ^ (((Pl1 >> 7) & 7) << 4);
  const int g0  = (L0 >> 7) * 1024 + (L0 & 127);
  const int g1  = (L1 >> 7) * 1024 + (L1 & 127);
  const char* Ab = (const char*)Xnb + (size_t)br * 262144;  // 256 rows x 1KB
  const char* Bb = (const char*)Ynb + (size_t)bc * 262144;

  // hoisted swizzled LDS read bases
  const int aswz = (l16 & 7) << 4;
  const int raB[2] = { (wr * 128 + l16) * 128 + ((lg * 16)      ^ aswz),
                       (wr * 128 + l16) * 128 + ((lg * 16 + 64) ^ aswz) };
  const int rbB[2] = { 32768 + (wc * 64 + l16) * 128 + ((lg * 16)      ^ aswz),
                       32768 + (wc * 64 + l16) * 128 + ((lg * 16 + 64) ^ aswz) };

  f32x4  acc[8][4] = {};
  bf16x8 af[2][2][4];   // [m-half][kslice][frag]
  bf16x8 bfr[2][4];     // [kslice][col-frag]

  // prologue: stage t0->buf0 and t1->buf1 (16 loads), wait t0 only (vmcnt(8)),
  // then read t0's first quadrant operands.
  STAGE_A(0, 0);
  STAGE_B(0, 0);
  STAGE_A((1 << 16), 1);
  STAGE_B((1 << 16), 1);
  asm volatile("s_waitcnt vmcnt(8)" ::: "memory");
  __builtin_amdgcn_s_barrier();
  asm volatile("" ::: "memory");
  READ_A(0, 0);
  READ_B(0, 0);

  for (int t = 0; t < 8; ++t) {               // K = 512 = 8 x BK(64)
    const int cur   = (t & 1) << 16;
    const int other = cur ^ (1 << 16);
    // ---- Ph1: finish reading tile t; Q(0,0) ----
    READ_A(cur, 1);
    READ_B(cur, 2);
    QUAD(0, 0);
    asm volatile("s_waitcnt lgkmcnt(0)" ::: "memory");  // all cur reads done
    __builtin_amdgcn_s_barrier();                       // -> cur is re-stageable
    // ---- Ph2: stage A(t+2) -> cur; Q(0,1) ----
    if (t < 6) STAGE_A(cur, t + 2);
    QUAD(0, 1);
    __builtin_amdgcn_s_barrier();
    // ---- Ph3: stage B(t+2) -> cur; Q(1,0) ----
    if (t < 6) STAGE_B(cur, t + 2);
    QUAD(1, 0);
    __builtin_amdgcn_s_barrier();
    // ---- Ph4: counted wait for t+1; read its first quadrant; Q(1,1) ----
    if (t < 6) {
      asm volatile("s_waitcnt vmcnt(8)" ::: "memory");  // t+1 landed, t+2 fly
    } else if (t == 6) {
      asm volatile("s_waitcnt vmcnt(0)" ::: "memory");  // tail: drain t7
    }
    __builtin_amdgcn_s_barrier();
    asm volatile("" ::: "memory");
    if (t < 7) {
      READ_A(other, 0);
      READ_B(other, 0);
    }
    QUAD(1, 1);
    __builtin_amdgcn_s_barrier();
  }

  // ---- epilogue: E = exp2(S*it - it); row/col partial sums (reuse sT) ----
  __syncthreads();
  float* rp = (float*)sT;            // [4][256]
  float* cp = (float*)(sT + 4096);   // [2][256]
  // D frag layout (m89): col = l16, row = lg*4 + reg within each 16x16
  float cacc[4] = {0.f, 0.f, 0.f, 0.f};
#pragma unroll
  for (int I = 0; I < 8; ++I) {
    float racc[4] = {0.f, 0.f, 0.f, 0.f};
#pragma unroll
    for (int J = 0; J < 4; ++J)
#pragma unroll
      for (int r = 0; r < 4; ++r) {
        const float e = exp2f(fmaf(acc[I][J][r], INV_T, -INV_T));
        racc[r] += e;
        cacc[J] += e;
      }
#pragma unroll
    for (int r = 0; r < 4; ++r) {
      float v = racc[r];
      v += __shfl_xor(v, 1); v += __shfl_xor(v, 2);
      v += __shfl_xor(v, 4); v += __shfl_xor(v, 8);
      if (l16 == 0) rp[wc * 256 + wr * 128 + I * 16 + lg * 4 + r] = v;
    }
  }
#pragma unroll
  for (int J = 0; J < 4; ++J) {
    float v = cacc[J];
    v += __shfl_xor(v, 16); v += __shfl_xor(v, 32);
    if (lg == 0) cp[wr * 256 + wc * 64 + J * 16 + l16] = v;
  }
  __syncthreads();
  if (tid < 256) {
    rowp[(size_t)bc * NB + br * 256 + tid] =
        rp[tid] + rp[256 + tid] + rp[512 + tid] + rp[768 + tid];
  } else {
    const int c = tid - 256;
    colp[(size_t)br * NB + bc * 256 + c] = cp[c] + cp[256 + c];
  }
}

// -------- kernel 3: reduce 32 partials per row/col, compute loss --------
__global__ __launch_bounds__(256) void loss_kernel(
    const float* __restrict__ rowp, const float* __restrict__ colp,
    const float* __restrict__ Sv, float* __restrict__ out) {
  __shared__ float wsum[4];
  const int i = blockIdx.x * 256 + threadIdx.x;
  float rs = 0.f, cs = 0.f;
#pragma unroll 4
  for (int b = 0; b < 32; ++b) {
    rs += rowp[(size_t)b * NB + i];
    cs += colp[(size_t)b * NB + i];
  }
  float v = 2.f * Sv[i] - logf(rs) - logf(cs);
#pragma unroll
  for (int m = 1; m < 64; m <<= 1) v += __shfl_xor(v, m);
  if ((threadIdx.x & 63) == 0) wsum[threadIdx.x >> 6] = v;
  __syncthreads();
  if (threadIdx.x == 0) {
    const float s = wsum[0] + wsum[1] + wsum[2] + wsum[3];
    atomicAdd(out, s * (-1.0f / (2.0f * NB)));
  }
}

extern "C" void kernel_launch(void* const* d_in, const int* in_sizes, int n_in,
                              void* d_out, int out_size, void* d_ws, size_t ws_size,
                              hipStream_t stream) {
  const float* X = (const float*)d_in[0];   // image_features
  const float* Y = (const float*)d_in[1];   // text_features
  char* ws = (char*)d_ws;
  // workspace layout (~19 MB)
  unsigned short* Xnb = (unsigned short*)(ws);                       // 8 MB
  unsigned short* Ynb = (unsigned short*)(ws + 8388608);             // 8 MB
  float* Sv   = (float*)(ws + 16777216);                             // 32 KB
  float* rowp = (float*)(ws + 16777216 + 32768);                     // 1 MB
  float* colp = (float*)(ws + 16777216 + 32768 + 1048576);           // 1 MB
  float* out  = (float*)d_out;

  (void)hipFuncSetAttribute((const void*)gemm_kernel,
                            hipFuncAttributeMaxDynamicSharedMemorySize,
                            131072);

  hipMemsetAsync(d_out, 0, sizeof(float), stream);
  norm_kernel2<<<NB / 4, 256, 0, stream>>>(X, Y, Xnb, Ynb, Sv);
  gemm_kernel<<<1024, 512, 131072, stream>>>(Xnb, Ynb, rowp, colp);
  loss_kernel<<<32, 256, 0, stream>>>(rowp, colp, Sv, out);
}